// Round 1
// baseline (322.660 us; speedup 1.0000x reference)
//
#include <hip/hip_runtime.h>
#include <hip/hip_bf16.h>

// GCN: h1 = relu(Â (x W1) + b1); h2 = relu(Â (h1 W2) + b2);
// out = mean_pool(h2, batch) @ Wlin + blin,  Â = D^-1/2 (A+I) D^-1/2
//
// R5/R6: bucketed CSR build, deterministic two-pass, zero global atomics.
// R7: xws bf16 -> agg row gather 128 B.
// R8/R9 LESSON: sub-dword per-lane global stores defeat L2 write-merge.
// R12 LESSON: multi-NODE gather unroll spills. One node context per wave.
// R14 LESSON: same-address atomic chains ~125 ns/link; keep <= ~100.
// R15/R16: replicated pooled accumulators (chunk=4, 32 replicas).
// R17: gather 16-edge tier, 8 row-gathers in flight per half-wave. 280 us.
// R18: dwordx2 gather (16 lanes/row, 4 edges/instr) + CSR padded to 4-slot
//     granularity with explicit self-loop slot + zero dummy row (idx N).
//     Node = whole instrs; issue-all tail puts an entire <=28-edge node in
//     flight in ONE dependent round. Halves VMEM instr count per edge.

#define NDIM 64
#define NGRAPH 64
#define NREP 32
#define BSHIFT 7                      // 128 nodes per bucket
#define BNODES 128
#define PADSLOT (BNODES * 4)          // max extra csr slots per bucket (self+3 dummies each)
#define ECHUNK 8192                   // edges per block in bincnt/bscatter (32/thread)

#define BLO(u) __uint_as_float((u) << 16)
#define BHI(u) __uint_as_float((u) & 0xFFFF0000u)

__device__ __forceinline__ unsigned short f32_to_bf16(float f) {
    unsigned int u = __float_as_uint(f);
    unsigned int r = 0x7FFFu + ((u >> 16) & 1u);   // round-to-nearest-even
    return (unsigned short)((u + r) >> 16);
}

// ---- pass 1: per-(block,bucket) edge counts via LDS histogram ----
__global__ void bincnt_k(const int* __restrict__ dst, int* __restrict__ cntmat,
                         int e, int nb) {
    extern __shared__ int hist[];
    int t = threadIdx.x;
    for (int i = t; i < nb; i += 256) hist[i] = 0;
    __syncthreads();
    int base = blockIdx.x * ECHUNK + t;
#pragma unroll
    for (int k = 0; k < 32; ++k) {
        int i = base + k * 256;
        if (i < e) atomicAdd(&hist[dst[i] >> BSHIFT], 1);   // LDS atomic
    }
    __syncthreads();
    long row = (long)blockIdx.x * nb;
    for (int i = t; i < nb; i += 256) cntmat[row + i] = hist[i];
}

// ---- pass 2: per-bucket exclusive scan across blocks (one block per bucket) ----
__global__ void colscan_k(const int* __restrict__ cntmat, int* __restrict__ basemat,
                          int* __restrict__ bucketTot, int nblk, int nb) {
    __shared__ int s[256];
    int b = blockIdx.x;
    int t = threadIdx.x;
    int v = (t < nblk) ? cntmat[(long)t * nb + b] : 0;
    s[t] = v;
    __syncthreads();
    for (int off = 1; off < 256; off <<= 1) {
        int tmp = (t >= off) ? s[t - off] : 0;
        __syncthreads();
        s[t] += tmp;
        __syncthreads();
    }
    if (t < nblk) basemat[(long)t * nb + b] = s[t] - v;   // exclusive within column
    if (t == 255) bucketTot[b] = s[255];
}

// ---- pass 3: exclusive scan of bucket totals (single block, nb<=1024) ----
__global__ void bscan_k(const int* __restrict__ bucketTot, int* __restrict__ bucketStart,
                        int* __restrict__ start, int nb, int n, int e) {
    __shared__ int s[1024];
    int t = threadIdx.x;
    int v = (t < nb) ? bucketTot[t] : 0;
    s[t] = v;
    __syncthreads();
    for (int off = 1; off < 1024; off <<= 1) {
        int tmp = (t >= off) ? s[t - off] : 0;
        __syncthreads();
        s[t] += tmp;
        __syncthreads();
    }
    if (t < nb) bucketStart[t + 1] = s[t];
    if (t == 0) { bucketStart[0] = 0; start[n] = e; }   // sentinel (unused by R18 gather)
}

// ---- pass 4: scatter packed (dst_local<<25 | src) via block-private LDS cursors ----
__global__ void bscatter_k(const int* __restrict__ src, const int* __restrict__ dst,
                           const int* __restrict__ bucketStart,
                           const int* __restrict__ basemat,
                           unsigned int* __restrict__ ebuf, int e, int nb) {
    extern __shared__ int cur[];
    int t = threadIdx.x;
    long row = (long)blockIdx.x * nb;
    for (int i = t; i < nb; i += 256) cur[i] = bucketStart[i] + basemat[row + i];
    __syncthreads();
    int base = blockIdx.x * ECHUNK + t;
#pragma unroll
    for (int k = 0; k < 32; ++k) {
        int i = base + k * 256;
        if (i < e) {
            int d = dst[i];
            int b = d >> BSHIFT;
            int pos = atomicAdd(&cur[b], 1);               // LDS atomic, block-private
            ebuf[pos] = ((unsigned)(d & (BNODES - 1)) << 25) | (unsigned)src[i];
        }
    }
}

// ---- pass 5: one block per bucket -> padded dst-ordered CSR slice, dinv, ranges ----
// R18: per-node slots = round_up(real_in_deg + 1(self), 4); bucket b's padded
// region starts at bucketStart[b] + b*PADSLOT. Pad slots point at zero row N.
__global__ void fill2_k(const unsigned int* __restrict__ ebuf,
                        const int* __restrict__ bucketStart,
                        const int* __restrict__ batch, float* __restrict__ dinv,
                        int* __restrict__ start, int* __restrict__ m4,
                        int* __restrict__ csr,
                        int* __restrict__ gstart, int* __restrict__ gend, int n) {
    __shared__ int scnt[BNODES], sincl[BNODES], scur[BNODES];
    int t = threadIdx.x;
    int b = blockIdx.x;
    int node0 = b << BSHIFT;
    int nNodes = min(BNODES, n - node0);
    if (t < BNODES) scnt[t] = 0;
    int e0 = bucketStart[b], e1 = bucketStart[b + 1];
    __syncthreads();
    for (int i = e0 + t; i < e1; i += 256)
        atomicAdd(&scnt[ebuf[i] >> 25], 1);
    __syncthreads();
    int val = (t < BNODES) ? scnt[t] : 0;
    int slots = (t < nNodes) ? ((val + 4) & ~3) : 0;   // real + self, padded to 4
    if (t < BNODES) sincl[t] = slots;
    __syncthreads();
    for (int off = 1; off < BNODES; off <<= 1) {
        int tmp = (t >= off && t < BNODES) ? sincl[t - off] : 0;
        __syncthreads();
        if (t < BNODES) sincl[t] += tmp;
        __syncthreads();
    }
    if (t < nNodes) {
        int v = node0 + t;
        int st = e0 + b * PADSLOT + sincl[t] - slots;   // exclusive scan, padded base
        start[v] = st;
        m4[v] = slots >> 2;                             // gather instrs per node
        scur[t] = st;
        dinv[v] = rsqrtf((float)(val + 1));
        csr[st + val] = v;                              // explicit self-loop slot
        for (int k2 = val + 1; k2 < slots; ++k2) csr[st + k2] = n;   // zero-row pads
        int g = batch[v];                 // sorted-batch boundary detection
        if (v == 0 || batch[v - 1] != g) gstart[g] = v;
        if (v == n - 1 || batch[v + 1] != g) gend[g] = v + 1;
    }
    __syncthreads();
    for (int i = e0 + t; i < e1; i += 256) {
        unsigned rec = ebuf[i];
        int pos = atomicAdd(&scur[rec >> 25], 1);
        csr[pos] = (int)(rec & 0x1FFFFFFu);   // scatter within L2-local slice
    }
}

// ---- dense GEMM v4  C[n,64](bf16 pairs) = scale[row] * (A[n,64] @ W[64,64]) ----
__global__ void gemm_k(const float* __restrict__ A, const float* __restrict__ W,
                       const float* __restrict__ scale,
                       unsigned long long* __restrict__ C, int n) {
    __shared__ float4 Wl4[64 * 16];   // 16 KB: W[k][4c..4c+3]
    __shared__ float4 Xl4[64 * 16];   // 16 KB: X[r][4k..4k+3]
    int t = threadIdx.x;
    const float4* W4 = (const float4*)W;
#pragma unroll
    for (int i = 0; i < 4; ++i) Wl4[t + 256 * i] = W4[t + 256 * i];
    const float4* A4 = (const float4*)A;
    long fbase = (long)blockIdx.x * 1024;
    long fmax  = (long)n * 16;
#pragma unroll
    for (int i = 0; i < 4; ++i) {
        long f = fbase + t + 256 * i;
        float4 v;
        if (f < fmax) v = A4[f];
        else { v.x = 0.f; v.y = 0.f; v.z = 0.f; v.w = 0.f; }
        Xl4[t + 256 * i] = v;
    }
    __syncthreads();
    int rg = t >> 4, cg = t & 15;
    float a00 = 0.f, a01 = 0.f, a02 = 0.f, a03 = 0.f;
    float a10 = 0.f, a11 = 0.f, a12 = 0.f, a13 = 0.f;
    float a20 = 0.f, a21 = 0.f, a22 = 0.f, a23 = 0.f;
    float a30 = 0.f, a31 = 0.f, a32 = 0.f, a33 = 0.f;
#pragma unroll 4
    for (int k4 = 0; k4 < 16; ++k4) {
        float4 w0 = Wl4[(4 * k4 + 0) * 16 + cg];
        float4 w1 = Wl4[(4 * k4 + 1) * 16 + cg];
        float4 w2 = Wl4[(4 * k4 + 2) * 16 + cg];
        float4 w3 = Wl4[(4 * k4 + 3) * 16 + cg];
        float4 x0 = Xl4[(4 * rg + 0) * 16 + k4];
        float4 x1 = Xl4[(4 * rg + 1) * 16 + k4];
        float4 x2 = Xl4[(4 * rg + 2) * 16 + k4];
        float4 x3 = Xl4[(4 * rg + 3) * 16 + k4];
        a00 += x0.x * w0.x + x0.y * w1.x + x0.z * w2.x + x0.w * w3.x;
        a01 += x0.x * w0.y + x0.y * w1.y + x0.z * w2.y + x0.w * w3.y;
        a02 += x0.x * w0.z + x0.y * w1.z + x0.z * w2.z + x0.w * w3.z;
        a03 += x0.x * w0.w + x0.y * w1.w + x0.z * w2.w + x0.w * w3.w;
        a10 += x1.x * w0.x + x1.y * w1.x + x1.z * w2.x + x1.w * w3.x;
        a11 += x1.x * w0.y + x1.y * w1.y + x1.z * w2.y + x1.w * w3.y;
        a12 += x1.x * w0.z + x1.y * w1.z + x1.z * w2.z + x1.w * w3.z;
        a13 += x1.x * w0.w + x1.y * w1.w + x1.z * w2.w + x1.w * w3.w;
        a20 += x2.x * w0.x + x2.y * w1.x + x2.z * w2.x + x2.w * w3.x;
        a21 += x2.x * w0.y + x2.y * w1.y + x2.z * w2.y + x2.w * w3.y;
        a22 += x2.x * w0.z + x2.y * w1.z + x2.z * w2.z + x2.w * w3.z;
        a23 += x2.x * w0.w + x2.y * w1.w + x2.z * w2.w + x2.w * w3.w;
        a30 += x3.x * w0.x + x3.y * w1.x + x3.z * w2.x + x3.w * w3.x;
        a31 += x3.x * w0.y + x3.y * w1.y + x3.z * w2.y + x3.w * w3.y;
        a32 += x3.x * w0.z + x3.y * w1.z + x3.z * w2.z + x3.w * w3.z;
        a33 += x3.x * w0.w + x3.y * w1.w + x3.z * w2.w + x3.w * w3.w;
    }
    int vb = blockIdx.x * 64 + rg * 4;
    int v;
    float s;
    unsigned long long u;
    v = vb + 0;
    if (v < n) {
        s = scale[v];
        u  = (unsigned long long)(((unsigned int)f32_to_bf16(s * a01) << 16) | (unsigned int)f32_to_bf16(s * a00));
        u |= (unsigned long long)(((unsigned int)f32_to_bf16(s * a03) << 16) | (unsigned int)f32_to_bf16(s * a02)) << 32;
        C[(long)v * 16 + cg] = u;
    }
    v = vb + 1;
    if (v < n) {
        s = scale[v];
        u  = (unsigned long long)(((unsigned int)f32_to_bf16(s * a11) << 16) | (unsigned int)f32_to_bf16(s * a10));
        u |= (unsigned long long)(((unsigned int)f32_to_bf16(s * a13) << 16) | (unsigned int)f32_to_bf16(s * a12)) << 32;
        C[(long)v * 16 + cg] = u;
    }
    v = vb + 2;
    if (v < n) {
        s = scale[v];
        u  = (unsigned long long)(((unsigned int)f32_to_bf16(s * a21) << 16) | (unsigned int)f32_to_bf16(s * a20));
        u |= (unsigned long long)(((unsigned int)f32_to_bf16(s * a23) << 16) | (unsigned int)f32_to_bf16(s * a22)) << 32;
        C[(long)v * 16 + cg] = u;
    }
    v = vb + 3;
    if (v < n) {
        s = scale[v];
        u  = (unsigned long long)(((unsigned int)f32_to_bf16(s * a31) << 16) | (unsigned int)f32_to_bf16(s * a30));
        u |= (unsigned long long)(((unsigned int)f32_to_bf16(s * a33) << 16) | (unsigned int)f32_to_bf16(s * a32)) << 32;
        C[(long)v * 16 + cg] = u;
    }
}

// ---- gather core v4 (R18): dwordx2, 16 lanes per row, 4 edges per instr.
// Lane: q=lane>>4 (edge slot within instr), r=lane&15 (dword pair -> dims
// 4r..4r+3). CSR is padded (self-loop + zero-row dummies) so every node is
// a whole number m of gather instrs. Main tier: 8 instrs (32 edges) in
// flight. Tail (m<=7, the common case at avg deg 16 -> m=5): issue ALL
// remaining j-loads then ALL row gathers before any consume -- whole node
// in flight in one dependent round. Returns full sums in every lane.
__device__ __forceinline__ void gather4(const unsigned int* __restrict__ xp,
                                        const int* __restrict__ csr,
                                        int s0, int m, int q, int r,
                                        float& o0, float& o1, float& o2, float& o3) {
    const uint2* __restrict__ xp2 = (const uint2*)xp;   // row = 16 uint2
    float a0 = 0.f, a1 = 0.f, a2 = 0.f, a3 = 0.f;
    float b0 = 0.f, b1 = 0.f, b2 = 0.f, b3 = 0.f;
    int c = s0 + q;
    while (m >= 8) {                      // 8 instrs = 32 edges in flight
        int j0 = csr[c +  0];
        int j1 = csr[c +  4];
        int j2 = csr[c +  8];
        int j3 = csr[c + 12];
        int j4 = csr[c + 16];
        int j5 = csr[c + 20];
        int j6 = csr[c + 24];
        int j7 = csr[c + 28];
        uint2 u0 = xp2[((unsigned)j0 << 4) + r];
        uint2 u1 = xp2[((unsigned)j1 << 4) + r];
        uint2 u2 = xp2[((unsigned)j2 << 4) + r];
        uint2 u3 = xp2[((unsigned)j3 << 4) + r];
        uint2 u4 = xp2[((unsigned)j4 << 4) + r];
        uint2 u5 = xp2[((unsigned)j5 << 4) + r];
        uint2 u6 = xp2[((unsigned)j6 << 4) + r];
        uint2 u7 = xp2[((unsigned)j7 << 4) + r];
        a0 += BLO(u0.x); a1 += BHI(u0.x); a2 += BLO(u0.y); a3 += BHI(u0.y);
        b0 += BLO(u1.x); b1 += BHI(u1.x); b2 += BLO(u1.y); b3 += BHI(u1.y);
        a0 += BLO(u2.x); a1 += BHI(u2.x); a2 += BLO(u2.y); a3 += BHI(u2.y);
        b0 += BLO(u3.x); b1 += BHI(u3.x); b2 += BLO(u3.y); b3 += BHI(u3.y);
        a0 += BLO(u4.x); a1 += BHI(u4.x); a2 += BLO(u4.y); a3 += BHI(u4.y);
        b0 += BLO(u5.x); b1 += BHI(u5.x); b2 += BLO(u5.y); b3 += BHI(u5.y);
        a0 += BLO(u6.x); a1 += BHI(u6.x); a2 += BLO(u6.y); a3 += BHI(u6.y);
        b0 += BLO(u7.x); b1 += BHI(u7.x); b2 += BLO(u7.y); b3 += BHI(u7.y);
        c += 32; m -= 8;
    }
    if (m > 0) {                          // tail: issue-all, consume after
        int j0, j1, j2, j3, j4, j5, j6;
        uint2 u0, u1, u2, u3, u4, u5, u6;
        j0 = csr[c];
        if (m > 1) j1 = csr[c +  4];
        if (m > 2) j2 = csr[c +  8];
        if (m > 3) j3 = csr[c + 12];
        if (m > 4) j4 = csr[c + 16];
        if (m > 5) j5 = csr[c + 20];
        if (m > 6) j6 = csr[c + 24];
        u0 = xp2[((unsigned)j0 << 4) + r];
        if (m > 1) u1 = xp2[((unsigned)j1 << 4) + r];
        if (m > 2) u2 = xp2[((unsigned)j2 << 4) + r];
        if (m > 3) u3 = xp2[((unsigned)j3 << 4) + r];
        if (m > 4) u4 = xp2[((unsigned)j4 << 4) + r];
        if (m > 5) u5 = xp2[((unsigned)j5 << 4) + r];
        if (m > 6) u6 = xp2[((unsigned)j6 << 4) + r];
        a0 += BLO(u0.x); a1 += BHI(u0.x); a2 += BLO(u0.y); a3 += BHI(u0.y);
        if (m > 1) { b0 += BLO(u1.x); b1 += BHI(u1.x); b2 += BLO(u1.y); b3 += BHI(u1.y); }
        if (m > 2) { a0 += BLO(u2.x); a1 += BHI(u2.x); a2 += BLO(u2.y); a3 += BHI(u2.y); }
        if (m > 3) { b0 += BLO(u3.x); b1 += BHI(u3.x); b2 += BLO(u3.y); b3 += BHI(u3.y); }
        if (m > 4) { a0 += BLO(u4.x); a1 += BHI(u4.x); a2 += BLO(u4.y); a3 += BHI(u4.y); }
        if (m > 5) { b0 += BLO(u5.x); b1 += BHI(u5.x); b2 += BLO(u5.y); b3 += BHI(u5.y); }
        if (m > 6) { a0 += BLO(u6.x); a1 += BHI(u6.x); a2 += BLO(u6.y); a3 += BHI(u6.y); }
    }
    a0 += b0; a1 += b1; a2 += b2; a3 += b3;
    a0 += __shfl_xor(a0, 16); a0 += __shfl_xor(a0, 32);   // fold 4 edge slots
    a1 += __shfl_xor(a1, 16); a1 += __shfl_xor(a1, 32);
    a2 += __shfl_xor(a2, 16); a2 += __shfl_xor(a2, 32);
    a3 += __shfl_xor(a3, 16); a3 += __shfl_xor(a3, 32);
    o0 = a0; o1 = a1; o2 = a2; o3 = a3;
}

// ---- aggregation (layer 1): out[v,:] = relu( dinv[v]*gather + b ), f32 out ----
__global__ void agg_k(const unsigned int* __restrict__ xp, const float* __restrict__ dinv,
                      const int* __restrict__ start, const int* __restrict__ m4,
                      const int* __restrict__ csr, const float* __restrict__ bias,
                      float* __restrict__ out, int n) {
    int t = threadIdx.x;
    int lane = t & 63;
    int q = lane >> 4, r = lane & 15;
    int v = blockIdx.x * 4 + (t >> 6);
    if (v >= n) return;
    int s0 = start[v], m = m4[v];
    float g0, g1, g2, g3;
    gather4(xp, csr, s0, m, q, r, g0, g1, g2, g3);
    float dv = dinv[v];
    float4 bb = ((const float4*)bias)[r];
    float4 o;
    o.x = fmaxf(fmaf(g0, dv, bb.x), 0.f);
    o.y = fmaxf(fmaf(g1, dv, bb.y), 0.f);
    o.z = fmaxf(fmaf(g2, dv, bb.z), 0.f);
    o.w = fmaxf(fmaf(g3, dv, bb.w), 0.f);
    if (q == 0) ((float4*)out)[(long)v * 16 + r] = o;   // 16 lanes x 16 B = row
}

// ---- aggpool v5: chunk=4 nodes/wave, 32x replicated pooled accumulator ----
__global__ void aggpool_k(const unsigned int* __restrict__ xp, const float* __restrict__ dinv,
                          const int* __restrict__ start, const int* __restrict__ m4,
                          const int* __restrict__ csr, const float* __restrict__ b2,
                          const int* __restrict__ batch, float* __restrict__ pooledR, int n) {
    int t = threadIdx.x;
    int lane = t & 63;
    int q = lane >> 4, r = lane & 15;
    int wid = blockIdx.x * 4 + (t >> 6);
    int v0 = wid * 4;
    if (v0 >= n) return;
    int v1 = min(v0 + 4, n);
    float4 bb = ((const float4*)b2)[r];
    long rbase = (long)(wid & (NREP - 1)) * (NGRAPH * NDIM);   // replica slice
    int gcur = -1;
    float p0 = 0.f, p1 = 0.f, p2 = 0.f, p3 = 0.f;
    for (int v = v0; v < v1; ++v) {
        int g = batch[v];                         // wave-uniform broadcast load
        if (g != gcur) {
            if (gcur >= 0 && q == 0) {
                atomicAdd(&pooledR[rbase + gcur * NDIM + 4 * r + 0], p0);
                atomicAdd(&pooledR[rbase + gcur * NDIM + 4 * r + 1], p1);
                atomicAdd(&pooledR[rbase + gcur * NDIM + 4 * r + 2], p2);
                atomicAdd(&pooledR[rbase + gcur * NDIM + 4 * r + 3], p3);
            }
            gcur = g;
            p0 = p1 = p2 = p3 = 0.f;
        }
        int s0 = start[v], m = m4[v];
        float g0, g1, g2, g3;
        gather4(xp, csr, s0, m, q, r, g0, g1, g2, g3);
        float dv = dinv[v];
        p0 += fmaxf(fmaf(g0, dv, bb.x), 0.f);
        p1 += fmaxf(fmaf(g1, dv, bb.y), 0.f);
        p2 += fmaxf(fmaf(g2, dv, bb.z), 0.f);
        p3 += fmaxf(fmaf(g3, dv, bb.w), 0.f);
    }
    if (gcur >= 0 && q == 0) {
        atomicAdd(&pooledR[rbase + gcur * NDIM + 4 * r + 0], p0);
        atomicAdd(&pooledR[rbase + gcur * NDIM + 4 * r + 1], p1);
        atomicAdd(&pooledR[rbase + gcur * NDIM + 4 * r + 2], p2);
        atomicAdd(&pooledR[rbase + gcur * NDIM + 4 * r + 3], p3);
    }
}

// ---- fold the 32 pooled replicas ----
__global__ void reduce_k(const float* __restrict__ pooledR, float* __restrict__ pooled) {
    int t = blockIdx.x * 256 + threadIdx.x;
    if (t >= NGRAPH * NDIM) return;
    float s = 0.f;
    for (int r = 0; r < NREP; ++r) s += pooledR[(long)r * (NGRAPH * NDIM) + t];
    pooled[t] = s;
}

// ---- head: out[g,c] = (pooled[g,:]/max(cnt,1)) @ Wlin + blin ----
__global__ void final_k(const float* __restrict__ pooled, const int* __restrict__ gstart,
                        const int* __restrict__ gend,
                        const float* __restrict__ Wlin, const float* __restrict__ blin,
                        float* __restrict__ out, int nclass) {
    int t = blockIdx.x * blockDim.x + threadIdx.x;
    if (t >= NGRAPH * nclass) return;
    int g = t / nclass, c = t % nclass;
    float cnt = (float)(gend[g] - gstart[g]);
    float inv = 1.f / fmaxf(cnt, 1.f);
    float acc = 0.f;
    for (int j = 0; j < NDIM; ++j) acc += pooled[g * NDIM + j] * Wlin[j * nclass + c];
    out[t] = acc * inv + blin[c];
}

extern "C" void kernel_launch(void* const* d_in, const int* in_sizes, int n_in,
                              void* d_out, int out_size, void* d_ws, size_t ws_size,
                              hipStream_t stream) {
    const float* x     = (const float*)d_in[0];
    const int*   ei    = (const int*)d_in[1];
    const int*   batch = (const int*)d_in[2];
    const float* W1    = (const float*)d_in[3];
    const float* b1    = (const float*)d_in[4];
    const float* W2    = (const float*)d_in[5];
    const float* b2    = (const float*)d_in[6];
    const float* Wlin  = (const float*)d_in[7];
    const float* blin  = (const float*)d_in[8];
    float* out = (float*)d_out;

    const int N = in_sizes[0] / NDIM;        // 100000
    const int E = in_sizes[1] / 2;           // 1600000
    const int NCLASS = in_sizes[7] / NDIM;   // 10
    const int* src = ei;
    const int* dst = ei + E;
    const int NB   = (N + BNODES - 1) >> BSHIFT;        // 782 buckets (<=1024)
    const int NBLK = (E + ECHUNK - 1) / ECHUNK;         // 196 edge blocks (<=256)

    // ---- workspace carve-out (each 256B-aligned) ----
    size_t o = 0;
    char* wsp = (char*)d_ws;
    auto take = [&](size_t nbytes) -> void* {
        void* p = (void*)(wsp + o);
        o += (nbytes + 255) & ~(size_t)255;
        return p;
    };
    int*   gstart    = (int*)take(NGRAPH * 4);
    int*   gend      = (int*)take(NGRAPH * 4);
    float* pooledR   = (float*)take((size_t)NREP * NGRAPH * NDIM * 4);   // 512 KB
    size_t zero_bytes = o;                    // everything above must start at 0
    float* pooled    = (float*)take(NGRAPH * NDIM * 4);
    int*   cntmat   = (int*)take((size_t)NBLK * NB * 4);
    int*   basemat  = (int*)take((size_t)NBLK * NB * 4);
    int*   bucketTot   = (int*)take((size_t)NB * 4);
    int*   bucketStart = (int*)take((size_t)(NB + 1) * 4);
    float* dinv  = (float*)take((size_t)N * 4);
    int*   start = (int*)take((size_t)(N + 1) * 4);
    int*   m4    = (int*)take((size_t)N * 4);
    int*   csr   = (int*)take(((size_t)E + (size_t)NB * PADSLOT + 64) * 4);  // padded CSR
    unsigned int* ebuf = (unsigned int*)take((size_t)E * 4);
    unsigned int* xws  = (unsigned int*)take((size_t)(N + 1) * NDIM * 2);  // bf16 pairs + zero row N
    float* h     = (float*)take((size_t)N * NDIM * 4);
    (void)ws_size;

    hipMemsetAsync(d_ws, 0, zero_bytes, stream);
    hipMemsetAsync((char*)xws + (size_t)N * NDIM * 2, 0, NDIM * 2, stream);  // dummy row

    int rbl = (N + 3) / 4;                    // 4 nodes per block (agg)
    int gbl = (N + 63) / 64;                  // 64 rows per block (gemm v4)
    int pbl = (N + 15) / 16;                  // aggpool: 4 waves x 4 nodes per block

    // CSR build (deterministic two-pass binning, zero global atomics)
    bincnt_k<<<NBLK, 256, (size_t)NB * 4, stream>>>(dst, cntmat, E, NB);
    colscan_k<<<NB, 256, 0, stream>>>(cntmat, basemat, bucketTot, NBLK, NB);
    bscan_k<<<1, 1024, 0, stream>>>(bucketTot, bucketStart, start, NB, N, E);
    bscatter_k<<<NBLK, 256, (size_t)NB * 4, stream>>>(src, dst, bucketStart, basemat, ebuf, E, NB);
    fill2_k<<<NB, 256, 0, stream>>>(ebuf, bucketStart, batch, dinv, start, m4, csr, gstart, gend, N);

    // layer 1
    gemm_k<<<gbl, 256, 0, stream>>>(x, W1, dinv, (unsigned long long*)xws, N);
    agg_k<<<rbl, 256, 0, stream>>>(xws, dinv, start, m4, csr, b1, h, N);
    // layer 2
    gemm_k<<<gbl, 256, 0, stream>>>(h, W2, dinv, (unsigned long long*)xws, N);
    // fused layer2-agg + replicated register mean-pool
    aggpool_k<<<pbl, 256, 0, stream>>>(xws, dinv, start, m4, csr, b2, batch, pooledR, N);
    reduce_k<<<(NGRAPH * NDIM + 255) / 256, 256, 0, stream>>>(pooledR, pooled);
    // head
    final_k<<<(NGRAPH * NCLASS + 255) / 256, 256, 0, stream>>>(pooled, gstart, gend, Wlin, blin, out, NCLASS);
}

// Round 2
// 276.606 us; speedup vs baseline: 1.1665x; 1.1665x over previous
//
#include <hip/hip_runtime.h>
#include <hip/hip_bf16.h>

// GCN: h1 = relu(Â (x W1) + b1); h2 = relu(Â (h1 W2) + b2);
// out = mean_pool(h2, batch) @ Wlin + blin,  Â = D^-1/2 (A+I) D^-1/2
//
// R5/R6: bucketed CSR build, deterministic two-pass, zero global atomics.
// R7: xws bf16 -> agg row gather 128 B.
// R8/R9 LESSON: sub-dword / strided per-lane global stores+atomics defeat
//     L2 write-merge (R18: 4x WRITE_SIZE from 16B-stride scalar atomics).
// R12 LESSON: multi-NODE gather unroll spills. One node context per wave.
// R14 LESSON: same-address atomic chains ~125 ns/link; keep <= ~100.
// R15/R16: replicated pooled accumulators (chunk=4, 32 replicas).
// R17: gather 16-edge tier, 8 row-gathers in flight per half-wave. 280 us.
// R18 LESSON: branchy issue-all tail -> path-dependent vmcnt -> compiler
//     drains vmcnt(0) at merges; killed the streaming pipeline. REVERTED.
// R19: keep R17 gather core EXACTLY (dword, 2 edges/instr, unconditional
//     8-in-flight body, precise vmcnt streaming) but pad CSR to 16-slot
//     granularity: self-loop is a real slot, pads point at zero row N.
//     Every node = m16 iterations of the main tier. No remainder tiers,
//     no self special-case, no branches.

#define NDIM 64
#define NGRAPH 64
#define NREP 32
#define BSHIFT 7                      // 128 nodes per bucket
#define BNODES 128
#define PADSLOT (BNODES * 16)         // worst-case extra csr slots per bucket
#define ECHUNK 8192                   // edges per block in bincnt/bscatter (32/thread)

#define BLO(u) __uint_as_float((u) << 16)
#define BHI(u) __uint_as_float((u) & 0xFFFF0000u)

__device__ __forceinline__ unsigned short f32_to_bf16(float f) {
    unsigned int u = __float_as_uint(f);
    unsigned int r = 0x7FFFu + ((u >> 16) & 1u);   // round-to-nearest-even
    return (unsigned short)((u + r) >> 16);
}

// ---- pass 1: per-(block,bucket) edge counts via LDS histogram ----
__global__ void bincnt_k(const int* __restrict__ dst, int* __restrict__ cntmat,
                         int e, int nb) {
    extern __shared__ int hist[];
    int t = threadIdx.x;
    for (int i = t; i < nb; i += 256) hist[i] = 0;
    __syncthreads();
    int base = blockIdx.x * ECHUNK + t;
#pragma unroll
    for (int k = 0; k < 32; ++k) {
        int i = base + k * 256;
        if (i < e) atomicAdd(&hist[dst[i] >> BSHIFT], 1);   // LDS atomic
    }
    __syncthreads();
    long row = (long)blockIdx.x * nb;
    for (int i = t; i < nb; i += 256) cntmat[row + i] = hist[i];
}

// ---- pass 2: per-bucket exclusive scan across blocks (one block per bucket) ----
__global__ void colscan_k(const int* __restrict__ cntmat, int* __restrict__ basemat,
                          int* __restrict__ bucketTot, int nblk, int nb) {
    __shared__ int s[256];
    int b = blockIdx.x;
    int t = threadIdx.x;
    int v = (t < nblk) ? cntmat[(long)t * nb + b] : 0;
    s[t] = v;
    __syncthreads();
    for (int off = 1; off < 256; off <<= 1) {
        int tmp = (t >= off) ? s[t - off] : 0;
        __syncthreads();
        s[t] += tmp;
        __syncthreads();
    }
    if (t < nblk) basemat[(long)t * nb + b] = s[t] - v;   // exclusive within column
    if (t == 255) bucketTot[b] = s[255];
}

// ---- pass 3: exclusive scan of bucket totals (single block, nb<=1024) ----
__global__ void bscan_k(const int* __restrict__ bucketTot, int* __restrict__ bucketStart,
                        int* __restrict__ start, int nb, int n, int e) {
    __shared__ int s[1024];
    int t = threadIdx.x;
    int v = (t < nb) ? bucketTot[t] : 0;
    s[t] = v;
    __syncthreads();
    for (int off = 1; off < 1024; off <<= 1) {
        int tmp = (t >= off) ? s[t - off] : 0;
        __syncthreads();
        s[t] += tmp;
        __syncthreads();
    }
    if (t < nb) bucketStart[t + 1] = s[t];
    if (t == 0) { bucketStart[0] = 0; start[n] = e; }   // sentinel (unused by gather)
}

// ---- pass 4: scatter packed (dst_local<<25 | src) via block-private LDS cursors ----
__global__ void bscatter_k(const int* __restrict__ src, const int* __restrict__ dst,
                           const int* __restrict__ bucketStart,
                           const int* __restrict__ basemat,
                           unsigned int* __restrict__ ebuf, int e, int nb) {
    extern __shared__ int cur[];
    int t = threadIdx.x;
    long row = (long)blockIdx.x * nb;
    for (int i = t; i < nb; i += 256) cur[i] = bucketStart[i] + basemat[row + i];
    __syncthreads();
    int base = blockIdx.x * ECHUNK + t;
#pragma unroll
    for (int k = 0; k < 32; ++k) {
        int i = base + k * 256;
        if (i < e) {
            int d = dst[i];
            int b = d >> BSHIFT;
            int pos = atomicAdd(&cur[b], 1);               // LDS atomic, block-private
            ebuf[pos] = ((unsigned)(d & (BNODES - 1)) << 25) | (unsigned)src[i];
        }
    }
}

// ---- pass 5: one block per bucket -> padded dst-ordered CSR slice, dinv, ranges ----
// R19: per-node slots = round_up(in_deg + 1(self), 16); bucket b's padded
// region starts at bucketStart[b] + b*PADSLOT. Pad slots point at zero row N.
__global__ void fill2_k(const unsigned int* __restrict__ ebuf,
                        const int* __restrict__ bucketStart,
                        const int* __restrict__ batch, float* __restrict__ dinv,
                        int* __restrict__ start, int* __restrict__ m16,
                        int* __restrict__ csr,
                        int* __restrict__ gstart, int* __restrict__ gend, int n) {
    __shared__ int scnt[BNODES], sincl[BNODES], scur[BNODES];
    int t = threadIdx.x;
    int b = blockIdx.x;
    int node0 = b << BSHIFT;
    int nNodes = min(BNODES, n - node0);
    if (t < BNODES) scnt[t] = 0;
    int e0 = bucketStart[b], e1 = bucketStart[b + 1];
    __syncthreads();
    for (int i = e0 + t; i < e1; i += 256)
        atomicAdd(&scnt[ebuf[i] >> 25], 1);
    __syncthreads();
    int val = (t < BNODES) ? scnt[t] : 0;
    int slots = (t < nNodes) ? ((val + 16) & ~15) : 0;   // real + self, padded to 16
    if (t < BNODES) sincl[t] = slots;
    __syncthreads();
    for (int off = 1; off < BNODES; off <<= 1) {
        int tmp = (t >= off && t < BNODES) ? sincl[t - off] : 0;
        __syncthreads();
        if (t < BNODES) sincl[t] += tmp;
        __syncthreads();
    }
    if (t < nNodes) {
        int v = node0 + t;
        int st = e0 + b * PADSLOT + sincl[t] - slots;   // exclusive scan, padded base
        start[v] = st;
        m16[v] = slots >> 4;                            // 16-edge tiers per node
        scur[t] = st;
        dinv[v] = rsqrtf((float)(val + 1));
        csr[st + val] = v;                              // explicit self-loop slot
        for (int k2 = val + 1; k2 < slots; ++k2) csr[st + k2] = n;   // zero-row pads
        int g = batch[v];                 // sorted-batch boundary detection
        if (v == 0 || batch[v - 1] != g) gstart[g] = v;
        if (v == n - 1 || batch[v + 1] != g) gend[g] = v + 1;
    }
    __syncthreads();
    for (int i = e0 + t; i < e1; i += 256) {
        unsigned rec = ebuf[i];
        int pos = atomicAdd(&scur[rec >> 25], 1);
        csr[pos] = (int)(rec & 0x1FFFFFFu);   // scatter within L2-local slice
    }
}

// ---- dense GEMM v4  C[n,64](bf16 pairs) = scale[row] * (A[n,64] @ W[64,64]) ----
__global__ void gemm_k(const float* __restrict__ A, const float* __restrict__ W,
                       const float* __restrict__ scale,
                       unsigned long long* __restrict__ C, int n) {
    __shared__ float4 Wl4[64 * 16];   // 16 KB: W[k][4c..4c+3]
    __shared__ float4 Xl4[64 * 16];   // 16 KB: X[r][4k..4k+3]
    int t = threadIdx.x;
    const float4* W4 = (const float4*)W;
#pragma unroll
    for (int i = 0; i < 4; ++i) Wl4[t + 256 * i] = W4[t + 256 * i];
    const float4* A4 = (const float4*)A;
    long fbase = (long)blockIdx.x * 1024;
    long fmax  = (long)n * 16;
#pragma unroll
    for (int i = 0; i < 4; ++i) {
        long f = fbase + t + 256 * i;
        float4 v;
        if (f < fmax) v = A4[f];
        else { v.x = 0.f; v.y = 0.f; v.z = 0.f; v.w = 0.f; }
        Xl4[t + 256 * i] = v;
    }
    __syncthreads();
    int rg = t >> 4, cg = t & 15;
    float a00 = 0.f, a01 = 0.f, a02 = 0.f, a03 = 0.f;
    float a10 = 0.f, a11 = 0.f, a12 = 0.f, a13 = 0.f;
    float a20 = 0.f, a21 = 0.f, a22 = 0.f, a23 = 0.f;
    float a30 = 0.f, a31 = 0.f, a32 = 0.f, a33 = 0.f;
#pragma unroll 4
    for (int k4 = 0; k4 < 16; ++k4) {
        float4 w0 = Wl4[(4 * k4 + 0) * 16 + cg];
        float4 w1 = Wl4[(4 * k4 + 1) * 16 + cg];
        float4 w2 = Wl4[(4 * k4 + 2) * 16 + cg];
        float4 w3 = Wl4[(4 * k4 + 3) * 16 + cg];
        float4 x0 = Xl4[(4 * rg + 0) * 16 + k4];
        float4 x1 = Xl4[(4 * rg + 1) * 16 + k4];
        float4 x2 = Xl4[(4 * rg + 2) * 16 + k4];
        float4 x3 = Xl4[(4 * rg + 3) * 16 + k4];
        a00 += x0.x * w0.x + x0.y * w1.x + x0.z * w2.x + x0.w * w3.x;
        a01 += x0.x * w0.y + x0.y * w1.y + x0.z * w2.y + x0.w * w3.y;
        a02 += x0.x * w0.z + x0.y * w1.z + x0.z * w2.z + x0.w * w3.z;
        a03 += x0.x * w0.w + x0.y * w1.w + x0.z * w2.w + x0.w * w3.w;
        a10 += x1.x * w0.x + x1.y * w1.x + x1.z * w2.x + x1.w * w3.x;
        a11 += x1.x * w0.y + x1.y * w1.y + x1.z * w2.y + x1.w * w3.y;
        a12 += x1.x * w0.z + x1.y * w1.z + x1.z * w2.z + x1.w * w3.z;
        a13 += x1.x * w0.w + x1.y * w1.w + x1.z * w2.w + x1.w * w3.w;
        a20 += x2.x * w0.x + x2.y * w1.x + x2.z * w2.x + x2.w * w3.x;
        a21 += x2.x * w0.y + x2.y * w1.y + x2.z * w2.y + x2.w * w3.y;
        a22 += x2.x * w0.z + x2.y * w1.z + x2.z * w2.z + x2.w * w3.z;
        a23 += x2.x * w0.w + x2.y * w1.w + x2.z * w2.w + x2.w * w3.w;
        a30 += x3.x * w0.x + x3.y * w1.x + x3.z * w2.x + x3.w * w3.x;
        a31 += x3.x * w0.y + x3.y * w1.y + x3.z * w2.y + x3.w * w3.y;
        a32 += x3.x * w0.z + x3.y * w1.z + x3.z * w2.z + x3.w * w3.z;
        a33 += x3.x * w0.w + x3.y * w1.w + x3.z * w2.w + x3.w * w3.w;
    }
    int vb = blockIdx.x * 64 + rg * 4;
    int v;
    float s;
    unsigned long long u;
    v = vb + 0;
    if (v < n) {
        s = scale[v];
        u  = (unsigned long long)(((unsigned int)f32_to_bf16(s * a01) << 16) | (unsigned int)f32_to_bf16(s * a00));
        u |= (unsigned long long)(((unsigned int)f32_to_bf16(s * a03) << 16) | (unsigned int)f32_to_bf16(s * a02)) << 32;
        C[(long)v * 16 + cg] = u;
    }
    v = vb + 1;
    if (v < n) {
        s = scale[v];
        u  = (unsigned long long)(((unsigned int)f32_to_bf16(s * a11) << 16) | (unsigned int)f32_to_bf16(s * a10));
        u |= (unsigned long long)(((unsigned int)f32_to_bf16(s * a13) << 16) | (unsigned int)f32_to_bf16(s * a12)) << 32;
        C[(long)v * 16 + cg] = u;
    }
    v = vb + 2;
    if (v < n) {
        s = scale[v];
        u  = (unsigned long long)(((unsigned int)f32_to_bf16(s * a21) << 16) | (unsigned int)f32_to_bf16(s * a20));
        u |= (unsigned long long)(((unsigned int)f32_to_bf16(s * a23) << 16) | (unsigned int)f32_to_bf16(s * a22)) << 32;
        C[(long)v * 16 + cg] = u;
    }
    v = vb + 3;
    if (v < n) {
        s = scale[v];
        u  = (unsigned long long)(((unsigned int)f32_to_bf16(s * a31) << 16) | (unsigned int)f32_to_bf16(s * a30));
        u |= (unsigned long long)(((unsigned int)f32_to_bf16(s * a33) << 16) | (unsigned int)f32_to_bf16(s * a32)) << 32;
        C[(long)v * 16 + cg] = u;
    }
}

// ---- gather core v5 (R19): R17's proven 16-edge tier, made the ONLY path.
// CSR padded to 16-slot multiples (self-loop + zero-row dummies), so the
// unconditional 8-in-flight body runs m16 times and nothing else. Lane:
// h=lane>>5 handles edges of parity h, p=lane&31 covers dim pair 2p/2p+1.
// All loads unconditional -> compiler emits precise streaming vmcnt.
__device__ __forceinline__ float gather_p(const unsigned int* __restrict__ xp,
                                          const int* __restrict__ csr,
                                          int s0, int m16, int h, int p) {
    float l0 = 0.f, l1 = 0.f, l2 = 0.f, l3 = 0.f;
    float h0 = 0.f, h1 = 0.f, h2 = 0.f, h3 = 0.f;
    int c = s0 + h;
    for (int it = 0; it < m16; ++it) {    // 8 row-gathers in flight per half-wave
        int j0 = csr[c +  0];
        int j1 = csr[c +  2];
        int j2 = csr[c +  4];
        int j3 = csr[c +  6];
        int j4 = csr[c +  8];
        int j5 = csr[c + 10];
        int j6 = csr[c + 12];
        int j7 = csr[c + 14];
        unsigned int u0 = xp[(long)j0 * 32 + p];
        unsigned int u1 = xp[(long)j1 * 32 + p];
        unsigned int u2 = xp[(long)j2 * 32 + p];
        unsigned int u3 = xp[(long)j3 * 32 + p];
        unsigned int u4 = xp[(long)j4 * 32 + p];
        unsigned int u5 = xp[(long)j5 * 32 + p];
        unsigned int u6 = xp[(long)j6 * 32 + p];
        unsigned int u7 = xp[(long)j7 * 32 + p];
        l0 += BLO(u0);  h0 += BHI(u0);
        l1 += BLO(u1);  h1 += BHI(u1);
        l2 += BLO(u2);  h2 += BHI(u2);
        l3 += BLO(u3);  h3 += BHI(u3);
        l0 += BLO(u4);  h0 += BHI(u4);
        l1 += BLO(u5);  h1 += BHI(u5);
        l2 += BLO(u6);  h2 += BHI(u6);
        l3 += BLO(u7);  h3 += BHI(u7);
        c += 16;
    }
    float al = (l0 + l1) + (l2 + l3);
    float ah = (h0 + h1) + (h2 + h3);
    al += __shfl_xor(al, 32);             // merge the two half-waves
    ah += __shfl_xor(ah, 32);
    return h ? ah : al;                   // value for dim d = 2p + h
}

// ---- aggregation (layer 1): out[v,:] = relu( dinv[v]*gather + b ), f32 out ----
__global__ void agg_k(const unsigned int* __restrict__ xp, const float* __restrict__ dinv,
                      const int* __restrict__ start, const int* __restrict__ m16,
                      const int* __restrict__ csr, const float* __restrict__ bias,
                      float* __restrict__ out, int n) {
    int t = threadIdx.x;
    int lane = t & 63;
    int h = lane >> 5;
    int p = lane & 31;
    int v = blockIdx.x * 4 + (t >> 6);
    if (v >= n) return;
    float sum = gather_p(xp, csr, start[v], m16[v], h, p);
    int d = 2 * p + h;
    float val = sum * dinv[v] + bias[d];
    out[(long)v * NDIM + d] = fmaxf(val, 0.f);
}

// ---- aggpool v6: chunk=4 nodes/wave, 32x replicated pooled accumulator ----
__global__ void aggpool_k(const unsigned int* __restrict__ xp, const float* __restrict__ dinv,
                          const int* __restrict__ start, const int* __restrict__ m16,
                          const int* __restrict__ csr, const float* __restrict__ b2,
                          const int* __restrict__ batch, float* __restrict__ pooledR, int n) {
    int t = threadIdx.x;
    int lane = t & 63;
    int h = lane >> 5, p = lane & 31;
    int wid = blockIdx.x * 4 + (t >> 6);
    int v0 = wid * 4;
    if (v0 >= n) return;
    int v1 = min(v0 + 4, n);
    int d = 2 * p + h;
    float bias = b2[d];
    long rbase = (long)(wid & (NREP - 1)) * (NGRAPH * NDIM);   // replica slice
    int gcur = -1;
    float acc = 0.f;
    for (int v = v0; v < v1; ++v) {
        int g = batch[v];                         // wave-uniform broadcast load
        if (g != gcur) {
            if (gcur >= 0) atomicAdd(&pooledR[rbase + gcur * NDIM + d], acc);
            gcur = g;
            acc = 0.f;
        }
        float sum = gather_p(xp, csr, start[v], m16[v], h, p);
        acc += fmaxf(sum * dinv[v] + bias, 0.f);
    }
    if (gcur >= 0) atomicAdd(&pooledR[rbase + gcur * NDIM + d], acc);
}

// ---- fold the 32 pooled replicas ----
__global__ void reduce_k(const float* __restrict__ pooledR, float* __restrict__ pooled) {
    int t = blockIdx.x * 256 + threadIdx.x;
    if (t >= NGRAPH * NDIM) return;
    float s = 0.f;
    for (int r = 0; r < NREP; ++r) s += pooledR[(long)r * (NGRAPH * NDIM) + t];
    pooled[t] = s;
}

// ---- head: out[g,c] = (pooled[g,:]/max(cnt,1)) @ Wlin + blin ----
__global__ void final_k(const float* __restrict__ pooled, const int* __restrict__ gstart,
                        const int* __restrict__ gend,
                        const float* __restrict__ Wlin, const float* __restrict__ blin,
                        float* __restrict__ out, int nclass) {
    int t = blockIdx.x * blockDim.x + threadIdx.x;
    if (t >= NGRAPH * nclass) return;
    int g = t / nclass, c = t % nclass;
    float cnt = (float)(gend[g] - gstart[g]);
    float inv = 1.f / fmaxf(cnt, 1.f);
    float acc = 0.f;
    for (int j = 0; j < NDIM; ++j) acc += pooled[g * NDIM + j] * Wlin[j * nclass + c];
    out[t] = acc * inv + blin[c];
}

extern "C" void kernel_launch(void* const* d_in, const int* in_sizes, int n_in,
                              void* d_out, int out_size, void* d_ws, size_t ws_size,
                              hipStream_t stream) {
    const float* x     = (const float*)d_in[0];
    const int*   ei    = (const int*)d_in[1];
    const int*   batch = (const int*)d_in[2];
    const float* W1    = (const float*)d_in[3];
    const float* b1    = (const float*)d_in[4];
    const float* W2    = (const float*)d_in[5];
    const float* b2    = (const float*)d_in[6];
    const float* Wlin  = (const float*)d_in[7];
    const float* blin  = (const float*)d_in[8];
    float* out = (float*)d_out;

    const int N = in_sizes[0] / NDIM;        // 100000
    const int E = in_sizes[1] / 2;           // 1600000
    const int NCLASS = in_sizes[7] / NDIM;   // 10
    const int* src = ei;
    const int* dst = ei + E;
    const int NB   = (N + BNODES - 1) >> BSHIFT;        // 782 buckets (<=1024)
    const int NBLK = (E + ECHUNK - 1) / ECHUNK;         // 196 edge blocks (<=256)

    // ---- workspace carve-out (each 256B-aligned) ----
    size_t o = 0;
    char* wsp = (char*)d_ws;
    auto take = [&](size_t nbytes) -> void* {
        void* p = (void*)(wsp + o);
        o += (nbytes + 255) & ~(size_t)255;
        return p;
    };
    int*   gstart    = (int*)take(NGRAPH * 4);
    int*   gend      = (int*)take(NGRAPH * 4);
    float* pooledR   = (float*)take((size_t)NREP * NGRAPH * NDIM * 4);   // 512 KB
    size_t zero_bytes = o;                    // everything above must start at 0
    float* pooled    = (float*)take(NGRAPH * NDIM * 4);
    int*   cntmat   = (int*)take((size_t)NBLK * NB * 4);
    int*   basemat  = (int*)take((size_t)NBLK * NB * 4);
    int*   bucketTot   = (int*)take((size_t)NB * 4);
    int*   bucketStart = (int*)take((size_t)(NB + 1) * 4);
    float* dinv  = (float*)take((size_t)N * 4);
    int*   start = (int*)take((size_t)(N + 1) * 4);
    int*   m16   = (int*)take((size_t)N * 4);
    int*   csr   = (int*)take(((size_t)E + (size_t)NB * PADSLOT + 64) * 4);  // padded CSR
    unsigned int* xws  = (unsigned int*)take((size_t)(N + 1) * NDIM * 2);  // bf16 pairs + zero row N
    float* h     = (float*)take((size_t)N * NDIM * 4);
    // ebuf is dead after fill2_k and h is written only after fill2_k:
    // alias ebuf onto h's region to keep the workspace footprint flat.
    unsigned int* ebuf = (unsigned int*)h;
    (void)ws_size;

    hipMemsetAsync(d_ws, 0, zero_bytes, stream);
    hipMemsetAsync((char*)xws + (size_t)N * NDIM * 2, 0, NDIM * 2, stream);  // dummy row

    int rbl = (N + 3) / 4;                    // 4 nodes per block (agg)
    int gbl = (N + 63) / 64;                  // 64 rows per block (gemm v4)
    int pbl = (N + 15) / 16;                  // aggpool: 4 waves x 4 nodes per block

    // CSR build (deterministic two-pass binning, zero global atomics)
    bincnt_k<<<NBLK, 256, (size_t)NB * 4, stream>>>(dst, cntmat, E, NB);
    colscan_k<<<NB, 256, 0, stream>>>(cntmat, basemat, bucketTot, NBLK, NB);
    bscan_k<<<1, 1024, 0, stream>>>(bucketTot, bucketStart, start, NB, N, E);
    bscatter_k<<<NBLK, 256, (size_t)NB * 4, stream>>>(src, dst, bucketStart, basemat, ebuf, E, NB);
    fill2_k<<<NB, 256, 0, stream>>>(ebuf, bucketStart, batch, dinv, start, m16, csr, gstart, gend, N);

    // layer 1
    gemm_k<<<gbl, 256, 0, stream>>>(x, W1, dinv, (unsigned long long*)xws, N);
    agg_k<<<rbl, 256, 0, stream>>>(xws, dinv, start, m16, csr, b1, h, N);
    // layer 2
    gemm_k<<<gbl, 256, 0, stream>>>(h, W2, dinv, (unsigned long long*)xws, N);
    // fused layer2-agg + replicated register mean-pool
    aggpool_k<<<pbl, 256, 0, stream>>>(xws, dinv, start, m16, csr, b2, batch, pooledR, N);
    reduce_k<<<(NGRAPH * NDIM + 255) / 256, 256, 0, stream>>>(pooledR, pooled);
    // head
    final_k<<<(NGRAPH * NCLASS + 255) / 256, 256, 0, stream>>>(pooled, gstart, gend, Wlin, blin, out, NCLASS);
}